// Round 3
// baseline (251.239 us; speedup 1.0000x reference)
//
#include <hip/hip_runtime.h>
#include <hip/hip_bf16.h>

typedef __bf16  bf16x8 __attribute__((ext_vector_type(8)));
typedef float   floatx4 __attribute__((ext_vector_type(4)));

#define GLOB_AS __attribute__((address_space(1)))
#define LDS_AS  __attribute__((address_space(3)))

__device__ __forceinline__ void async_copy16(void* l, const void* g) {
  __builtin_amdgcn_global_load_lds((const GLOB_AS void*)g, (LDS_AS void*)l, 16, 0, 0);
}

#define BAR()       __builtin_amdgcn_s_barrier()
#define WAIT_VM(N)  asm volatile("s_waitcnt vmcnt(" #N ")" ::: "memory")

// ---------------- fused prep kernel ----------------
// blocks 0..895     : x (32,256,28,28) fp32 -> xT bf16 NHWC
// blocks 896..1919  : prototypes -> wT bf16 [p][(kh*3+kw)*256+c], ps_sq[p]
// blocks 1920..2815 : sq[b][h][w] = sum_c x^2 (exact fp32)
__global__ __launch_bounds__(256) void prep_all(const float* __restrict__ x,
                                                const float* __restrict__ w,
                                                __hip_bfloat16* __restrict__ xT,
                                                __hip_bfloat16* __restrict__ wT,
                                                float* __restrict__ ps,
                                                float* __restrict__ sq) {
  __shared__ __hip_bfloat16 tile[28][256];
  __shared__ float wbuf[2304];
  __shared__ float redw[256];
  __shared__ float reds[256];

  const int bid = blockIdx.x;
  const int tid = threadIdx.x;

  if (bid < 896) {
    const int b = bid / 28, h = bid - b * 28;
    const float* src = x + (((long)b * 256 + tid) * 28 + h) * 28;
#pragma unroll
    for (int ww = 0; ww < 28; ++ww) tile[ww][tid] = __float2bfloat16(src[ww]);
    __syncthreads();
    __hip_bfloat16* dst = xT + ((long)(b * 28 + h) * 28) * 256 + tid;
#pragma unroll
    for (int ww = 0; ww < 28; ++ww) dst[ww * 256] = tile[ww][tid];
  } else if (bid < 1920) {
    const int p = bid - 896;
    const float* src = w + (long)p * 2304;
#pragma unroll
    for (int r = 0; r < 9; ++r) wbuf[r * 256 + tid] = src[r * 256 + tid];
    __syncthreads();
    float s = 0.f;
#pragma unroll
    for (int t = 0; t < 9; ++t) {
      float v = wbuf[tid * 9 + t];
      s += v * v;
      wT[(long)p * 2304 + t * 256 + tid] = __float2bfloat16(v);
    }
    redw[tid] = s;
    __syncthreads();
    for (int off = 128; off > 0; off >>= 1) {
      if (tid < off) redw[tid] += redw[tid + off];
      __syncthreads();
    }
    if (tid == 0) ps[p] = redw[0];
  } else {
    const int bh = bid - 1920;
    const int b = bh / 28, h = bh - b * 28;
    const int ww = tid & 31, grp = tid >> 5;   // 8 groups x 32 channels
    float s = 0.f;
    if (ww < 28) {
      const float* src = x + (((long)b * 256 + grp * 32) * 28 + h) * 28 + ww;
      for (int cc = 0; cc < 32; ++cc) {
        float v = src[(long)cc * 784];
        s += v * v;
      }
    }
    reds[tid] = s;
    __syncthreads();
    if (tid < 32) {
      float v = 0.f;
#pragma unroll
      for (int g = 0; g < 8; ++g) v += reds[g * 32 + tid];
      if (tid < 28) sq[bh * 28 + tid] = v;
    }
  }
}

// ---------------- main kernel: ring-3, ONE barrier per K-tile, wave-desynced ----------------
// C[p][pix] = sum_k wT[p][k] * xTpatch[pix][k]; BM=256 BN=128 BK=64, 8 waves (4Mx2N, 64x64 each).
// LDS stage (48 KB): A[256][64] bf16 | B[128][64] bf16, XOR-swizzled rows of 128B.
__global__ __launch_bounds__(512, 1) void l2_main(
    const __hip_bfloat16* __restrict__ wT,   // [1024][2304]
    const __hip_bfloat16* __restrict__ xT,   // [32][28][28][256]
    const float* __restrict__ ps_sq,         // [1024]
    const float* __restrict__ sq,            // [32][28][28]
    float* __restrict__ out)                 // [32][1024][676]
{
  __shared__ __attribute__((aligned(16))) char lds[3 * 49152];

  const int tid = threadIdx.x;
  const int wv = tid >> 6;
  const int lane = tid & 63;

  // T1: bijective XCD-chunk swizzle (676 = 4*85 + 4*84)
  const int bid = blockIdx.x;
  const int xcd = bid & 7, loc = bid >> 3;
  const int wg = (xcd < 4 ? xcd * 85 : 340 + (xcd - 4) * 84) + loc;
  const int py = wg / 169;
  const int nx = wg - py * 169;
  const int p0 = py << 8;      // proto base
  const int n0 = nx << 7;      // pixel base

  // ---- staging addresses (T2: inverse-swizzled global source, linear LDS dest) ----
  const int l8 = lane >> 3;                       // row-within-8
  const int kbyte = ((lane & 7) << 4) ^ (l8 << 4);
  const int ke = kbyte >> 1;                      // element offset (mult of 8)

  const __hip_bfloat16* aSrc0 = wT + (long)(p0 +   0 + wv * 8 + l8) * 2304 + ke;
  const __hip_bfloat16* aSrc1 = wT + (long)(p0 +  64 + wv * 8 + l8) * 2304 + ke;
  const __hip_bfloat16* aSrc2 = wT + (long)(p0 + 128 + wv * 8 + l8) * 2304 + ke;
  const __hip_bfloat16* aSrc3 = wT + (long)(p0 + 192 + wv * 8 + l8) * 2304 + ke;

  const __hip_bfloat16 *bSrc0, *bSrc1;
  {
    int pix = n0 + wv * 8 + l8;
    int b = pix / 676, e = pix - b * 676;
    int oh = e / 26, ow = e - oh * 26;
    bSrc0 = xT + (long)((b * 28 + oh) * 28 + ow) * 256 + ke;
    pix += 64;
    b = pix / 676; e = pix - b * 676; oh = e / 26; ow = e - oh * 26;
    bSrc1 = xT + (long)((b * 28 + oh) * 28 + ow) * 256 + ke;
  }

  const int aD0 = wv * 1024, aD1 = 8192 + wv * 1024;
  const int aD2 = 16384 + wv * 1024, aD3 = 24576 + wv * 1024;
  const int bD0 = 32768 + wv * 1024, bD1 = 40960 + wv * 1024;

  auto kOffB = [](int kt) {
    int s = kt >> 2;
    int sh = s / 3, sw2 = s - 3 * sh;
    return (sh * 28 + sw2) * 256 + ((kt & 3) << 6);
  };
  auto stageTile = [&](int kt, int sb) {
    const long ka = (long)kt << 6;
    const int kb2 = kOffB(kt);
    async_copy16(lds + sb + aD0, aSrc0 + ka);
    async_copy16(lds + sb + aD1, aSrc1 + ka);
    async_copy16(lds + sb + aD2, aSrc2 + ka);
    async_copy16(lds + sb + aD3, aSrc3 + ka);
    async_copy16(lds + sb + bD0, bSrc0 + kb2);
    async_copy16(lds + sb + bD1, bSrc1 + kb2);
  };

  // ---- fragment read addressing (swizzled) ----
  const int ln15 = lane & 15;
  const int swz = (lane & 7) << 4;
  const int kh0 = ((lane >> 4) << 4) ^ swz;           // k-half 0 byte offset
  const int kh1 = (64 + ((lane >> 4) << 4)) ^ swz;    // k-half 1
  const int aRowB = ((wv >> 1) * 64 + ln15) * 128;
  const int bRowB = 32768 + ((wv & 1) * 64 + ln15) * 128;

  floatx4 acc[4][4];
#pragma unroll
  for (int i = 0; i < 4; ++i)
#pragma unroll
    for (int j = 0; j < 4; ++j) acc[i][j] = (floatx4){0.f, 0.f, 0.f, 0.f};

  // per-wave k-half traversal order: odd waves reversed (desync LDS vs MFMA bursts)
  const int kfirst = (wv & 1) ? kh1 : kh0;
  const int ksecond = (wv & 1) ? kh0 : kh1;

  auto computeHalf = [&](int curS, int kOff) {
    bf16x8 af[4], bq[4];
#pragma unroll
    for (int i = 0; i < 4; ++i)
      af[i] = *(const bf16x8*)(lds + curS + aRowB + i * 2048 + kOff);
#pragma unroll
    for (int j = 0; j < 4; ++j)
      bq[j] = *(const bf16x8*)(lds + curS + bRowB + j * 2048 + kOff);
    __builtin_amdgcn_s_setprio(1);
#pragma unroll
    for (int i = 0; i < 4; ++i)
#pragma unroll
      for (int j = 0; j < 4; ++j)
        acc[i][j] = __builtin_amdgcn_mfma_f32_16x16x32_bf16(af[i], bq[j], acc[i][j], 0, 0, 0);
    __builtin_amdgcn_s_setprio(0);
  };

  // prologue: tiles 0 and 1 in flight (12 loads each wave)
  stageTile(0, 0);
  stageTile(1, 49152);

  int curS = 0, stgS = 2 * 49152;
  for (int t = 0; t < 36; ++t) {
    if (t < 35) { WAIT_VM(6); } else { WAIT_VM(0); }
    BAR();                      // all waves: stage(t) landed, tile t-1 reads done
    if (t < 34) stageTile(t + 2, stgS);
    computeHalf(curS, kfirst);
    computeHalf(curS, ksecond);
    curS += 49152; if (curS == 147456) curS = 0;
    stgS += 49152; if (stgS == 147456) stgS = 0;
  }

  // ---- epilogue: d = sqrt(max(xs_box + ps - 2*acc, 1e-14)), box filter folded in ----
  const int pixBase = n0 + (wv & 1) * 64 + ln15;
  const int rowBase = p0 + (wv >> 1) * 64 + ((lane >> 4) << 2);

  float psv[4][4];
#pragma unroll
  for (int i = 0; i < 4; ++i)
#pragma unroll
    for (int rr = 0; rr < 4; ++rr) psv[i][rr] = ps_sq[rowBase + i * 16 + rr];

#pragma unroll
  for (int j = 0; j < 4; ++j) {
    const int pix = pixBase + j * 16;
    const int b = pix / 676;
    const int pb = pix - b * 676;
    const int oh = pb / 26, ow = pb - oh * 26;
    const float* sp = sq + (b * 28 + oh) * 28 + ow;
    float xs = 0.f;
#pragma unroll
    for (int kh = 0; kh < 3; ++kh)
#pragma unroll
      for (int kw = 0; kw < 3; ++kw) xs += sp[kh * 28 + kw];
    float* op = out + (long)b * 676 * 1024 + pb;
#pragma unroll
    for (int i = 0; i < 4; ++i)
#pragma unroll
      for (int rr = 0; rr < 4; ++rr) {
        float d2 = xs + psv[i][rr] - 2.0f * acc[i][j][rr];
        op[(long)(rowBase + i * 16 + rr) * 676] = sqrtf(fmaxf(d2, 1e-14f));
      }
  }
}

// ---------------- launcher ----------------

extern "C" void kernel_launch(void* const* d_in, const int* in_sizes, int n_in,
                              void* d_out, int out_size, void* d_ws, size_t ws_size,
                              hipStream_t stream) {
  const float* x = (const float*)d_in[0];        // (32,256,28,28)
  const float* w = (const float*)d_in[1];        // (1024,256,3,3)
  float* out = (float*)d_out;                    // (32,1024,26,26)

  char* ws = (char*)d_ws;
  __hip_bfloat16* wT = (__hip_bfloat16*)ws;                       // 4,718,592 B
  __hip_bfloat16* xT = (__hip_bfloat16*)(ws + 4718592);           // 12,845,056 B
  float* ps = (float*)(ws + 17563648);                            // 4,096 B
  float* sq = (float*)(ws + 17567744);                            // 100,352 B

  prep_all<<<2816, 256, 0, stream>>>(x, w, xT, wT, ps, sq);
  l2_main<<<676, 512, 0, stream>>>(wT, xT, ps, sq, out);
}

// Round 4
// 241.365 us; speedup vs baseline: 1.0409x; 1.0409x over previous
//
#include <hip/hip_runtime.h>
#include <hip/hip_bf16.h>

typedef __bf16  bf16x8 __attribute__((ext_vector_type(8)));
typedef float   floatx4 __attribute__((ext_vector_type(4)));

#define GLOB_AS __attribute__((address_space(1)))
#define LDS_AS  __attribute__((address_space(3)))

__device__ __forceinline__ void async_copy16(void* l, const void* g) {
  __builtin_amdgcn_global_load_lds((const GLOB_AS void*)g, (LDS_AS void*)l, 16, 0, 0);
}

#define BAR()       __builtin_amdgcn_s_barrier()
#define WAIT_VM(N)  asm volatile("s_waitcnt vmcnt(" #N ")" ::: "memory")

// ---------------- fused prep kernel ----------------
// blocks 0..511    : x NCHW fp32 -> xT bf16 NHWC, + per-hw sum of squares (atomicAdd into sq)
// blocks 512..1535 : prototypes -> wT bf16 [p][(kh*3+kw)*256+c], ps_sq[p]
__global__ __launch_bounds__(256) void prep_all(const float* __restrict__ x,
                                                const float* __restrict__ w,
                                                __hip_bfloat16* __restrict__ xT,
                                                __hip_bfloat16* __restrict__ wT,
                                                float* __restrict__ ps,
                                                float* __restrict__ sq) {
  __shared__ __align__(16) float shm[12864];   // 51456 B, aliased per path

  const int bid = blockIdx.x;
  const int tid = threadIdx.x;

  if (bid < 512) {
    // ---- x path: tile = x[b, c0:c0+64, hw0:hw0+196] staged in LDS [64][201]
    const int b = bid >> 4;
    const int sub = bid & 15;
    const int c0 = (sub >> 2) * 64, hw0 = (sub & 3) * 196;
    float (*tile)[201] = (float(*)[201])shm;
    const float* xs = x + ((long)(b * 256 + c0)) * 784 + hw0;
#pragma unroll
    for (int i = 0; i < 49; ++i) {            // 49*256 = 12544 = 64*196, coalesced
      int idx = i * 256 + tid;
      int c = idx / 196, r = idx - c * 196;
      tile[c][r] = xs[(long)c * 784 + r];
    }
    __syncthreads();
#pragma unroll
    for (int i = 0; i < 49; ++i) {            // write: consecutive tid -> consecutive c
      int idx = i * 256 + tid;
      int hw = idx >> 6, c = idx & 63;
      xT[((long)(b * 784 + hw0 + hw)) * 256 + c0 + c] = __float2bfloat16(tile[c][hw]);
    }
    if (tid < 196) {                           // fused sum-of-squares (64-c partial)
      float s = 0.f;
#pragma unroll
      for (int c = 0; c < 64; ++c) { float v = tile[c][tid]; s += v * v; }
      atomicAdd(&sq[b * 784 + hw0 + tid], s);
    }
  } else {
    // ---- w path
    const int p = bid - 512;
    float* wbuf = shm;            // 2304
    float* redw = shm + 2304;     // 256
    const float* src = w + (long)p * 2304;
#pragma unroll
    for (int r = 0; r < 9; ++r) wbuf[r * 256 + tid] = src[r * 256 + tid];
    __syncthreads();
    float s = 0.f;
#pragma unroll
    for (int t = 0; t < 9; ++t) {
      float v = wbuf[tid * 9 + t];
      s += v * v;
      wT[(long)p * 2304 + t * 256 + tid] = __float2bfloat16(v);
    }
    redw[tid] = s;
    __syncthreads();
    for (int off = 128; off > 0; off >>= 1) {
      if (tid < off) redw[tid] += redw[tid + off];
      __syncthreads();
    }
    if (tid == 0) ps[p] = redw[0];
  }
}

// ---------------- main kernel ----------------
// C[p][pix] = sum_k wT[p][k]*xTpatch[pix][k]. BM=256 BN=128 BK=32.
// 4 waves (2M x 2N), wave-tile 128x64. Ring-3 x 24KB stages -> 72KB LDS, 2 blocks/CU.
// Stage rows are 64B (4 x 16B chunks), chunk-swizzled: slot cs holds chunk cs^((row>>1)&3).
__global__ __launch_bounds__(256, 2) void l2_main(
    const __hip_bfloat16* __restrict__ wT,   // [1024][2304]
    const __hip_bfloat16* __restrict__ xT,   // [32][784][256]
    const float* __restrict__ ps_sq,         // [1024]
    const float* __restrict__ sq,            // [32][784]
    float* __restrict__ out)                 // [32][1024][676]
{
  __shared__ __attribute__((aligned(16))) char lds[73728];

  const int tid = threadIdx.x;
  const int wv = tid >> 6;
  const int lane = tid & 63;

  // T1: bijective XCD-chunk swizzle (676 = 4*85 + 4*84)
  const int bid = blockIdx.x;
  const int xcd = bid & 7, loc = bid >> 3;
  const int wg = (xcd < 4 ? xcd * 85 : 340 + (xcd - 4) * 84) + loc;
  const int py = wg / 169;
  const int nx = wg - py * 169;
  const int p0 = py << 8;      // proto base (4 tiles of 256)
  const int n0 = nx << 7;      // pixel base (169 tiles of 128)

  // ---- staging: lane -> (row-in-16, chunk-slot); source pre-swizzled
  const int lrow = lane >> 2, lcs = lane & 3;
  const int cg = lcs ^ ((lrow >> 1) & 3);     // global chunk fetched into slot lcs

  const __hip_bfloat16* aS0 = wT + (long)(p0 + wv * 64 +  0 + lrow) * 2304 + cg * 8;
  const __hip_bfloat16* aS1 = wT + (long)(p0 + wv * 64 + 16 + lrow) * 2304 + cg * 8;
  const __hip_bfloat16* aS2 = wT + (long)(p0 + wv * 64 + 32 + lrow) * 2304 + cg * 8;
  const __hip_bfloat16* aS3 = wT + (long)(p0 + wv * 64 + 48 + lrow) * 2304 + cg * 8;
  const int aD0 = wv * 4096, aD1 = wv * 4096 + 1024;
  const int aD2 = wv * 4096 + 2048, aD3 = wv * 4096 + 3072;

  const __hip_bfloat16 *bS0, *bS1;
  {
    int pix = n0 + wv * 32 + lrow;
    int b = pix / 676, e = pix - b * 676;
    bS0 = xT + ((long)b * 784 + (e / 26) * 28 + (e % 26)) * 256 + cg * 8;
    pix += 16;
    b = pix / 676; e = pix - b * 676;
    bS1 = xT + ((long)b * 784 + (e / 26) * 28 + (e % 26)) * 256 + cg * 8;
  }
  const int bD0 = 16384 + wv * 2048, bD1 = 16384 + wv * 2048 + 1024;

  auto stage = [&](int kt, int sb) {
    const long ka = (long)kt << 5;                       // A: k walks linearly
    const int sl = kt >> 3;
    const int sh = sl / 3, sw2 = sl - 3 * sh;
    const int kb = (sh * 28 + sw2) * 256 + ((kt & 7) << 5);
    async_copy16(lds + sb + aD0, aS0 + ka);
    async_copy16(lds + sb + aD1, aS1 + ka);
    async_copy16(lds + sb + aD2, aS2 + ka);
    async_copy16(lds + sb + aD3, aS3 + ka);
    async_copy16(lds + sb + bD0, bS0 + kb);
    async_copy16(lds + sb + bD1, bS1 + kb);
  };

  // ---- fragment read addressing (swizzle matches staging)
  const int ln15 = lane & 15;
  const int kb2 = (((lane >> 4) ^ ((ln15 >> 1) & 3)) << 4);  // swizzled 16B chunk in 64B row
  const int wm = wv >> 1, wn = wv & 1;
  const int aBase = wm * 8192 + ln15 * 64 + kb2;             // + i*1024
  const int bBase = 16384 + wn * 4096 + ln15 * 64 + kb2;     // + j*1024

  floatx4 acc[8][4];
#pragma unroll
  for (int i = 0; i < 8; ++i)
#pragma unroll
    for (int j = 0; j < 4; ++j) acc[i][j] = (floatx4){0.f, 0.f, 0.f, 0.f};

  // prologue: tiles 0,1 in flight (12 loads/wave)
  stage(0, 0);
  stage(1, 24576);

  int curS = 0, stgS = 49152;
  for (int t = 0; t < 72; ++t) {
    if (t < 71) { WAIT_VM(6); } else { WAIT_VM(0); }
    BAR();                                  // stage(t) landed everywhere; t-1 reads done
    if (t < 70) stage(t + 2, stgS);

    bf16x8 af[8], bq[4];
#pragma unroll
    for (int i = 0; i < 8; ++i)
      af[i] = *(const bf16x8*)(lds + curS + aBase + i * 1024);
#pragma unroll
    for (int j = 0; j < 4; ++j)
      bq[j] = *(const bf16x8*)(lds + curS + bBase + j * 1024);

    __builtin_amdgcn_s_setprio(1);
#pragma unroll
    for (int i = 0; i < 8; ++i)
#pragma unroll
      for (int j = 0; j < 4; ++j)
        acc[i][j] = __builtin_amdgcn_mfma_f32_16x16x32_bf16(af[i], bq[j], acc[i][j], 0, 0, 0);
    __builtin_amdgcn_s_setprio(0);

    curS += 24576; if (curS == 73728) curS = 0;
    stgS += 24576; if (stgS == 73728) stgS = 0;
  }

  // ---- epilogue: d = sqrt(max(box(sq) + ps - 2*acc, 1e-14))
  const int pixBase = n0 + wn * 64 + ln15;
  const int rowBase = p0 + wm * 128 + ((lane >> 4) << 2);

#pragma unroll
  for (int j = 0; j < 4; ++j) {
    const int pix = pixBase + j * 16;
    const int b = pix / 676;
    const int pb = pix - b * 676;
    const int oh = pb / 26, ow = pb - oh * 26;
    const float* sp = sq + b * 784 + oh * 28 + ow;
    float xs = 0.f;
#pragma unroll
    for (int kh = 0; kh < 3; ++kh)
#pragma unroll
      for (int kw = 0; kw < 3; ++kw) xs += sp[kh * 28 + kw];
    float* op = out + (long)b * 692224 + pb;   // 676*1024
#pragma unroll
    for (int i = 0; i < 8; ++i) {
      const int p = rowBase + i * 16;
#pragma unroll
      for (int rr = 0; rr < 4; ++rr) {
        float d2 = xs + ps_sq[p + rr] - 2.0f * acc[i][j][rr];
        op[(long)(p + rr) * 676] = sqrtf(fmaxf(d2, 1e-14f));
      }
    }
  }
}

// ---------------- launcher ----------------

extern "C" void kernel_launch(void* const* d_in, const int* in_sizes, int n_in,
                              void* d_out, int out_size, void* d_ws, size_t ws_size,
                              hipStream_t stream) {
  const float* x = (const float*)d_in[0];        // (32,256,28,28)
  const float* w = (const float*)d_in[1];        // (1024,256,3,3)
  float* out = (float*)d_out;                    // (32,1024,26,26)

  char* ws = (char*)d_ws;
  __hip_bfloat16* wT = (__hip_bfloat16*)ws;                       // 4,718,592 B
  __hip_bfloat16* xT = (__hip_bfloat16*)(ws + 4718592);           // 12,845,056 B
  float* ps = (float*)(ws + 17563648);                            // 4,096 B
  float* sq = (float*)(ws + 17567744);                            // 100,352 B

  hipMemsetAsync(sq, 0, 32 * 784 * 4, stream);                    // sq accumulated via atomics
  prep_all<<<1536, 256, 0, stream>>>(x, w, xT, wT, ps, sq);
  l2_main<<<676, 256, 0, stream>>>(wT, xT, ps, sq, out);
}